// Round 12
// baseline (62.661 us; speedup 1.0000x reference)
//
#include <hip/hip_runtime.h>

#define HW 224
#define CHW (HW*HW)

__global__ __launch_bounds__(128) void patch_conv_kernel(
    const float* __restrict__ X,    // [B][3][224][224]
    const float* __restrict__ Wt,   // [3][3][3][3] OIHW
    const float* __restrict__ Bv,   // [3]
    const float* __restrict__ P,    // [3136][48]
    float* __restrict__ out)        // [B][196][768]
{
    const int tid  = threadIdx.x;
    const int lane = tid & 63;
    const int wv   = tid >> 6;                  // 0..1
    const int b    = blockIdx.y;
    const int y0   = blockIdx.x * 16 + wv * 8;  // wave owns rows y0..y0+7 (4 pairs)
    const int x0   = lane * 4;                  // 0..252
    const bool act = (x0 < HW);                 // lanes 56..63 assist shfl only

    // ---- once per wave: weights (wave-uniform -> SGPRs) + bias
    float w[81];
    #pragma unroll
    for (int i = 0; i < 81; ++i) w[i] = Wt[i];
    const float bias[3] = { Bv[0], Bv[1], Bv[2] };

    const float* Xb = X + (size_t)b * (3 * CHW);
    float* ob = out + (size_t)b * (196 * 768);

    // ---- prime: rows y0-1 .. y0+2 (4 rows x 3 ch = 12 loads)
    float4 v[3][4];
    #pragma unroll
    for (int ci = 0; ci < 3; ++ci) {
        #pragma unroll
        for (int rj = 0; rj < 4; ++rj) {
            const int ry = y0 - 1 + rj;
            float4 t = make_float4(0.f, 0.f, 0.f, 0.f);
            if ((unsigned)ry < HW && act)
                t = *(const float4*)(Xb + ci * CHW + ry * HW + x0);
            v[ci][rj] = t;
        }
    }

    #pragma unroll
    for (int k = 0; k < 4; ++k) {
        const int y = y0 + 2 * k;               // even

        // 1) issue next pair's 6 new X loads (rows y+3, y+4) — consumed at k+1
        float4 nv[3][2];
        if (k < 3) {
            #pragma unroll
            for (int ci = 0; ci < 3; ++ci) {
                #pragma unroll
                for (int rj = 0; rj < 2; ++rj) {
                    const int ry = y + 3 + rj;
                    float4 t = make_float4(0.f, 0.f, 0.f, 0.f);
                    if ((unsigned)ry < HW && act)
                        t = *(const float4*)(Xb + ci * CHW + ry * HW + x0);
                    nv[ci][rj] = t;
                }
            }
        }

        // 2) issue P loads now, consume AFTER the FMA block (~1300 cy cover)
        const int nf   = (y >> 2) * 56 + lane;  // lane == x0>>2
        const int sub0 = (y & 3) * 4;           // 0 or 8
        float4 pr[2][3];
        #pragma unroll
        for (int rr = 0; rr < 2; ++rr) {
            #pragma unroll
            for (int co = 0; co < 3; ++co) {
                float4 t = make_float4(0.f, 0.f, 0.f, 0.f);
                if (act)
                    t = *(const float4*)(P + nf * 48 + co * 16 + sub0 + rr * 4);
                pr[rr][co] = t;
            }
        }

        // 3) edges via shfl (v[.][2..3] were loaded one iteration ago)
        float win[3][4][6];
        #pragma unroll
        for (int ci = 0; ci < 3; ++ci) {
            #pragma unroll
            for (int rj = 0; rj < 4; ++rj) {
                float lf = __shfl_up(v[ci][rj].w, 1);
                float rt = __shfl_down(v[ci][rj].x, 1);
                if (lane == 0) lf = 0.f;
                if (x0 + 4 >= HW) rt = 0.f;
                win[ci][rj][0] = lf;
                win[ci][rj][1] = v[ci][rj].x; win[ci][rj][2] = v[ci][rj].y;
                win[ci][rj][3] = v[ci][rj].z; win[ci][rj][4] = v[ci][rj].w;
                win[ci][rj][5] = rt;
            }
        }

        // 4) 648 FMAs from zero (no dependency on P)
        float acc[2][3][4];
        #pragma unroll
        for (int rr = 0; rr < 2; ++rr)
            #pragma unroll
            for (int co = 0; co < 3; ++co)
                #pragma unroll
                for (int j = 0; j < 4; ++j) acc[rr][co][j] = 0.f;

        #pragma unroll
        for (int ci = 0; ci < 3; ++ci) {
            #pragma unroll
            for (int ky = 0; ky < 3; ++ky) {
                const float* r0 = win[ci][ky];
                const float* r1 = win[ci][ky + 1];
                #pragma unroll
                for (int co = 0; co < 3; ++co) {
                    const float w0 = w[((co * 3 + ci) * 3 + ky) * 3 + 0];
                    const float w1 = w[((co * 3 + ci) * 3 + ky) * 3 + 1];
                    const float w2 = w[((co * 3 + ci) * 3 + ky) * 3 + 2];
                    #pragma unroll
                    for (int j = 0; j < 4; ++j) {
                        acc[0][co][j] += w0 * r0[j] + w1 * r0[j + 1] + w2 * r0[j + 2];
                        acc[1][co][j] += w0 * r1[j] + w1 * r1[j + 1] + w2 * r1[j + 2];
                    }
                }
            }
        }

        // 5) add bias + P (P arrived during the FMA block), then store
        if (act) {
            const int nc = (y >> 4) * 14 + (x0 >> 4);
            float* opb = ob + nc * 768 + (x0 & 15);
            #pragma unroll
            for (int rr = 0; rr < 2; ++rr) {
                float* op = opb + ((y + rr) & 15) * 16;
                #pragma unroll
                for (int co = 0; co < 3; ++co)
                    *(float4*)(op + co * 256) = make_float4(
                        acc[rr][co][0] + bias[co] + pr[rr][co].x,
                        acc[rr][co][1] + bias[co] + pr[rr][co].y,
                        acc[rr][co][2] + bias[co] + pr[rr][co].z,
                        acc[rr][co][3] + bias[co] + pr[rr][co].w);
            }
        }

        // 6) shift the rolling window (static indices only)
        if (k < 3) {
            #pragma unroll
            for (int ci = 0; ci < 3; ++ci) {
                v[ci][0] = v[ci][2];
                v[ci][1] = v[ci][3];
                v[ci][2] = nv[ci][0];
                v[ci][3] = nv[ci][1];
            }
        }
    }
}

extern "C" void kernel_launch(void* const* d_in, const int* in_sizes, int n_in,
                              void* d_out, int out_size, void* d_ws, size_t ws_size,
                              hipStream_t stream) {
    const float* X  = (const float*)d_in[0];
    const float* Wt = (const float*)d_in[1];
    const float* Bv = (const float*)d_in[2];
    const float* P  = (const float*)d_in[3];
    float* out = (float*)d_out;

    // wave = 8 rows (4 pipelined pairs); block = 2 waves = 16 rows.
    // grid = 14 x 128 = 1792 blocks = exactly 7 blocks/CU (balanced).
    dim3 grid(14, 128);
    patch_conv_kernel<<<grid, 128, 0, stream>>>(X, Wt, Bv, P, out);
}

// Round 14
// 39.832 us; speedup vs baseline: 1.5731x; 1.5731x over previous
//
#include <hip/hip_runtime.h>

#define HW 224
#define CHW (HW*HW)

typedef float f32x4 __attribute__((ext_vector_type(4)));

__global__ __launch_bounds__(256) void patch_conv_kernel(
    const float* __restrict__ X,    // [B][3][224][224]
    const float* __restrict__ Wt,   // [3][3][3][3] OIHW
    const float* __restrict__ Bv,   // [3]
    const float* __restrict__ P,    // [3136][48]
    float* __restrict__ out)        // [B][196][768]
{
    const int tid  = threadIdx.x;
    const int lane = tid & 63;
    const int wv   = tid >> 6;
    const int b    = blockIdx.y;
    const int y0   = blockIdx.x * 8 + wv * 2;   // even; wave owns rows y0, y0+1
    const int x0   = lane * 4;                  // 0..252
    const bool act = (x0 < HW);                 // lanes 56..63 assist shfl only

    // ---- weights: wave-uniform -> SGPRs
    float w[81];
    #pragma unroll
    for (int i = 0; i < 81; ++i) w[i] = Wt[i];

    const float* Xb = X + (size_t)b * (3 * CHW);

    // ---- issue ALL 12 X loads up-front (rows y0-1..y0+2 x 3 channels)
    float4 v[3][4];
    #pragma unroll
    for (int ci = 0; ci < 3; ++ci) {
        #pragma unroll
        for (int rj = 0; rj < 4; ++rj) {
            const int ry = y0 - 1 + rj;
            float4 t = make_float4(0.f, 0.f, 0.f, 0.f);
            if ((unsigned)ry < HW && act)
                t = *(const float4*)(Xb + ci * CHW + ry * HW + x0);
            v[ci][rj] = t;
        }
    }

    // ---- 6 P loads, also up-front (rows y0,y0+1 in the SAME fine row: y0 even)
    const int nf   = (y0 >> 2) * 56 + lane;     // lane == x0>>2
    const int sub0 = (y0 & 3) * 4;              // 0 or 8
    float4 pr[2][3];
    #pragma unroll
    for (int rr = 0; rr < 2; ++rr) {
        #pragma unroll
        for (int co = 0; co < 3; ++co) {
            float4 t = make_float4(0.f, 0.f, 0.f, 0.f);
            if (act)
                t = *(const float4*)(P + nf * 48 + co * 16 + sub0 + rr * 4);
            pr[rr][co] = t;
        }
    }

    // ---- edges via shfl (all 64 lanes participate)
    float win[3][4][6];
    #pragma unroll
    for (int ci = 0; ci < 3; ++ci) {
        #pragma unroll
        for (int rj = 0; rj < 4; ++rj) {
            float lf = __shfl_up(v[ci][rj].w, 1);
            float rt = __shfl_down(v[ci][rj].x, 1);
            if (lane == 0) lf = 0.f;
            if (x0 + 4 >= HW) rt = 0.f;
            win[ci][rj][0] = lf;
            win[ci][rj][1] = v[ci][rj].x; win[ci][rj][2] = v[ci][rj].y;
            win[ci][rj][3] = v[ci][rj].z; win[ci][rj][4] = v[ci][rj].w;
            win[ci][rj][5] = rt;
        }
    }

    if (!act) return;

    // ---- accumulators: bias + P
    float acc[2][3][4];
    #pragma unroll
    for (int rr = 0; rr < 2; ++rr) {
        #pragma unroll
        for (int co = 0; co < 3; ++co) {
            const float bb = Bv[co];
            acc[rr][co][0] = bb + pr[rr][co].x;
            acc[rr][co][1] = bb + pr[rr][co].y;
            acc[rr][co][2] = bb + pr[rr][co].z;
            acc[rr][co][3] = bb + pr[rr][co].w;
        }
    }

    // ---- 648 FMAs: row0 uses win[.][ky], row1 uses win[.][ky+1]
    #pragma unroll
    for (int ci = 0; ci < 3; ++ci) {
        #pragma unroll
        for (int ky = 0; ky < 3; ++ky) {
            const float* r0 = win[ci][ky];
            const float* r1 = win[ci][ky + 1];
            #pragma unroll
            for (int co = 0; co < 3; ++co) {
                const float w0 = w[((co * 3 + ci) * 3 + ky) * 3 + 0];
                const float w1 = w[((co * 3 + ci) * 3 + ky) * 3 + 1];
                const float w2 = w[((co * 3 + ci) * 3 + ky) * 3 + 2];
                #pragma unroll
                for (int j = 0; j < 4; ++j) {
                    acc[0][co][j] += w0 * r0[j] + w1 * r0[j + 1] + w2 * r0[j + 2];
                    acc[1][co][j] += w0 * r1[j] + w1 * r1[j + 1] + w2 * r1[j + 2];
                }
            }
        }
    }

    // ---- stores: nontemporal (out is write-only; don't churn L2/L3, keep X resident)
    const int nc = (y0 >> 4) * 14 + (x0 >> 4);
    float* opb = out + (size_t)b * (196 * 768) + nc * 768 + (x0 & 15);
    #pragma unroll
    for (int rr = 0; rr < 2; ++rr) {
        float* op = opb + ((y0 + rr) & 15) * 16;
        #pragma unroll
        for (int co = 0; co < 3; ++co) {
            f32x4 t = { acc[rr][co][0], acc[rr][co][1],
                        acc[rr][co][2], acc[rr][co][3] };
            __builtin_nontemporal_store(t, (f32x4*)(op + co * 256));
        }
    }
}

extern "C" void kernel_launch(void* const* d_in, const int* in_sizes, int n_in,
                              void* d_out, int out_size, void* d_ws, size_t ws_size,
                              hipStream_t stream) {
    const float* X  = (const float*)d_in[0];
    const float* Wt = (const float*)d_in[1];
    const float* Bv = (const float*)d_in[2];
    const float* P  = (const float*)d_in[3];
    float* out = (float*)d_out;

    // wave = 2 rows; block = 4 waves = 8 rows; 28 x-blocks x 128 images
    dim3 grid(28, 128);
    patch_conv_kernel<<<grid, 256, 0, stream>>>(X, Wt, Bv, P, out);
}

// Round 15
// 38.275 us; speedup vs baseline: 1.6371x; 1.0407x over previous
//
#include <hip/hip_runtime.h>

#define HW 224
#define CHW (HW*HW)
#define NBLK (28 * 128)

__global__ __launch_bounds__(256) void patch_conv_kernel(
    const float* __restrict__ X,    // [B][3][224][224]
    const float* __restrict__ Wt,   // [3][3][3][3] OIHW
    const float* __restrict__ Bv,   // [3]
    const float* __restrict__ P,    // [3136][48]
    float* __restrict__ out)        // [B][196][768]
{
    const int tid  = threadIdx.x;
    const int lane = tid & 63;
    const int wv   = tid >> 6;

    // XCD-aware bijective swizzle: consecutive blockIdx round-robin across the
    // 8 XCDs; remap so each XCD gets 448 contiguous work items = 16 whole
    // images -> strip halos + P slice become per-XCD L2 hits.
    const int n    = blockIdx.x;                // 0..3583
    const int swz  = (n & 7) * (NBLK / 8) + (n >> 3);
    const int strip = swz % 28;                 // 8-row strip within image
    const int b     = swz / 28;                 // image 0..127

    const int y0   = strip * 8 + wv * 2;        // even; wave owns rows y0, y0+1
    const int x0   = lane * 4;                  // 0..252
    const bool act = (x0 < HW);                 // lanes 56..63 assist shfl only

    // ---- weights: wave-uniform -> SGPRs
    float w[81];
    #pragma unroll
    for (int i = 0; i < 81; ++i) w[i] = Wt[i];

    const float* Xb = X + (size_t)b * (3 * CHW);

    // ---- issue ALL 12 X loads up-front (rows y0-1..y0+2 x 3 channels)
    float4 v[3][4];
    #pragma unroll
    for (int ci = 0; ci < 3; ++ci) {
        #pragma unroll
        for (int rj = 0; rj < 4; ++rj) {
            const int ry = y0 - 1 + rj;
            float4 t = make_float4(0.f, 0.f, 0.f, 0.f);
            if ((unsigned)ry < HW && act)
                t = *(const float4*)(Xb + ci * CHW + ry * HW + x0);
            v[ci][rj] = t;
        }
    }

    // ---- 6 P loads, also up-front (rows y0,y0+1 in the SAME fine row: y0 even)
    const int nf   = (y0 >> 2) * 56 + lane;     // lane == x0>>2
    const int sub0 = (y0 & 3) * 4;              // 0 or 8
    float4 pr[2][3];
    #pragma unroll
    for (int rr = 0; rr < 2; ++rr) {
        #pragma unroll
        for (int co = 0; co < 3; ++co) {
            float4 t = make_float4(0.f, 0.f, 0.f, 0.f);
            if (act)
                t = *(const float4*)(P + nf * 48 + co * 16 + sub0 + rr * 4);
            pr[rr][co] = t;
        }
    }

    // ---- edges via shfl (all 64 lanes participate)
    float win[3][4][6];
    #pragma unroll
    for (int ci = 0; ci < 3; ++ci) {
        #pragma unroll
        for (int rj = 0; rj < 4; ++rj) {
            float lf = __shfl_up(v[ci][rj].w, 1);
            float rt = __shfl_down(v[ci][rj].x, 1);
            if (lane == 0) lf = 0.f;
            if (x0 + 4 >= HW) rt = 0.f;
            win[ci][rj][0] = lf;
            win[ci][rj][1] = v[ci][rj].x; win[ci][rj][2] = v[ci][rj].y;
            win[ci][rj][3] = v[ci][rj].z; win[ci][rj][4] = v[ci][rj].w;
            win[ci][rj][5] = rt;
        }
    }

    if (!act) return;

    // ---- accumulators: bias + P
    float acc[2][3][4];
    #pragma unroll
    for (int rr = 0; rr < 2; ++rr) {
        #pragma unroll
        for (int co = 0; co < 3; ++co) {
            const float bb = Bv[co];
            acc[rr][co][0] = bb + pr[rr][co].x;
            acc[rr][co][1] = bb + pr[rr][co].y;
            acc[rr][co][2] = bb + pr[rr][co].z;
            acc[rr][co][3] = bb + pr[rr][co].w;
        }
    }

    // ---- 648 FMAs: row0 uses win[.][ky], row1 uses win[.][ky+1]
    #pragma unroll
    for (int ci = 0; ci < 3; ++ci) {
        #pragma unroll
        for (int ky = 0; ky < 3; ++ky) {
            const float* r0 = win[ci][ky];
            const float* r1 = win[ci][ky + 1];
            #pragma unroll
            for (int co = 0; co < 3; ++co) {
                const float w0 = w[((co * 3 + ci) * 3 + ky) * 3 + 0];
                const float w1 = w[((co * 3 + ci) * 3 + ky) * 3 + 1];
                const float w2 = w[((co * 3 + ci) * 3 + ky) * 3 + 2];
                #pragma unroll
                for (int j = 0; j < 4; ++j) {
                    acc[0][co][j] += w0 * r0[j] + w1 * r0[j + 1] + w2 * r0[j + 2];
                    acc[1][co][j] += w0 * r1[j] + w1 * r1[j + 1] + w2 * r1[j + 2];
                }
            }
        }
    }

    // ---- stores: both rows share the same coarse patch (y0 even)
    const int nc = (y0 >> 4) * 14 + (x0 >> 4);
    float* opb = out + (size_t)b * (196 * 768) + nc * 768 + (x0 & 15);
    #pragma unroll
    for (int rr = 0; rr < 2; ++rr) {
        float* op = opb + ((y0 + rr) & 15) * 16;
        #pragma unroll
        for (int co = 0; co < 3; ++co)
            *(float4*)(op + co * 256) =
                make_float4(acc[rr][co][0], acc[rr][co][1],
                            acc[rr][co][2], acc[rr][co][3]);
    }
}

extern "C" void kernel_launch(void* const* d_in, const int* in_sizes, int n_in,
                              void* d_out, int out_size, void* d_ws, size_t ws_size,
                              hipStream_t stream) {
    const float* X  = (const float*)d_in[0];
    const float* Wt = (const float*)d_in[1];
    const float* Bv = (const float*)d_in[2];
    const float* P  = (const float*)d_in[3];
    float* out = (float*)d_out;

    // wave = 2 rows; block = 4 waves = 8 rows; 1D grid with XCD-chunked swizzle
    patch_conv_kernel<<<NBLK, 256, 0, stream>>>(X, Wt, Bv, P, out);
}